// Round 2
// baseline (43841.180 us; speedup 1.0000x reference)
//
#include <hip/hip_runtime.h>

#define BSZ  128
#define TLEN 256
#define NH   1024
#define SLOT (BSZ*NH)
#define NWG  256

using bf16x8 = __attribute__((ext_vector_type(8))) short;
using f32x4  = __attribute__((ext_vector_type(4))) float;

__device__ inline short f2bf(float f){
  union {float f; unsigned u;} v; v.f = f;
  unsigned r = v.u + 0x7fffu + ((v.u >> 16) & 1u);
  return (short)(r >> 16);
}
__device__ inline float sigf(float x){ return 1.f/(1.f+__expf(-x)); }

// Device-scope grid barrier: monotonically increasing epoch counter, one arrival
// per WG. Release fence (L2 writeback) before arrival, acquire fence (L1 inv)
// after release from spin, so cross-XCD state writes are visible.
__device__ inline void gsync(unsigned* cnt, unsigned target){
  __syncthreads();
  if (threadIdx.x == 0){
    __builtin_amdgcn_fence(__ATOMIC_RELEASE, "agent");
    __hip_atomic_fetch_add(cnt, 1u, __ATOMIC_RELAXED, __HIP_MEMORY_SCOPE_AGENT);
    while (__hip_atomic_load(cnt, __ATOMIC_RELAXED, __HIP_MEMORY_SCOPE_AGENT) < target)
      __builtin_amdgcn_s_sleep(1);
  }
  __syncthreads();
  __builtin_amdgcn_fence(__ATOMIC_ACQUIRE, "agent");
}

// Transpose-convert: D[n][k] (bf16) = S[k][n] (f32), S is K x 2048, per blockIdx.z matrix.
__global__ __launch_bounds__(256) void transpose_bf16(const float* __restrict__ src,
                                                      short* __restrict__ dst, int K){
  const size_t mat = blockIdx.z;
  const float* S = src + mat * (size_t)K * 2048;
  short* D = dst + mat * (size_t)K * 2048;
  __shared__ float tile[32][33];
  int n0 = blockIdx.x * 32;
  int k0 = blockIdx.y * 32;
  int tx = threadIdx.x & 31, ty = threadIdx.x >> 5;
  #pragma unroll
  for (int i=0;i<4;i++)
    tile[ty + i*8][tx] = S[(size_t)(k0 + ty + i*8)*2048 + n0 + tx];
  __syncthreads();
  #pragma unroll
  for (int i=0;i<4;i++){
    int n = n0 + ty + i*8;
    D[(size_t)n*K + k0 + tx] = f2bf(tile[tx][ty + i*8]);
  }
}

__global__ __launch_bounds__(256) void init_h(const float* __restrict__ h0,
                                              float* __restrict__ hF, short* __restrict__ hB){
  int i = blockIdx.x*256 + threadIdx.x;
  float v = h0[i];
  hF[i] = v; hB[i] = f2bf(v);
}

// Fused NG-gene matmul over one 16-row x 16-colpair tile, K=1024.
// A (bf16) shared across genes. Weights: WsT + gene*2^21, H-half rows at +2^20.
template<int NG>
__device__ inline void mm_g(const short* __restrict__ Ab, const short* __restrict__ WsT,
                            const int (&gs)[NG], int col0, int r0, int m, int q,
                            f32x4 (&aC)[NG], f32x4 (&aH)[NG])
{
  const short* ap = Ab + ((size_t)(r0+m) << 10) + (q << 3);
  const short* wp[NG];
  #pragma unroll
  for (int g=0; g<NG; g++)
    wp[g] = WsT + ((size_t)gs[g] << 21) + ((size_t)(col0+m) << 10) + (q << 3);
  #pragma unroll 2
  for (int k0=0; k0<1024; k0+=32){
    bf16x8 a = *(const bf16x8*)(ap + k0);
    #pragma unroll
    for (int g=0; g<NG; g++){
      bf16x8 bc = *(const bf16x8*)(wp[g] + k0);
      bf16x8 bh = *(const bf16x8*)(wp[g] + (1u<<20) + k0);
      aC[g] = __builtin_amdgcn_mfma_f32_16x16x32_bf16(a, bc, aC[g], 0, 0, 0);
      aH[g] = __builtin_amdgcn_mfma_f32_16x16x32_bf16(a, bh, aH[g], 0, 0, 0);
    }
  }
}

__global__ __launch_bounds__(256) void rnn_persistent(
    const float* __restrict__ x, const short* __restrict__ W0T,
    const short* __restrict__ WsT, float* __restrict__ F,
    short* __restrict__ Bb, float* __restrict__ out, unsigned* __restrict__ cnt)
{
  const int wg   = blockIdx.x;
  const int wv   = threadIdx.x >> 6;
  const int lane = threadIdx.x & 63;
  const int m = lane & 15, q = lane >> 4;

  float* s0F = F;          float* s1F = F + SLOT;   float* s2F = F + 2*SLOT;
  float* s3F = F + 3*SLOT; float* s4F = F + 4*SLOT; float* s5F = F + 5*SLOT;
  float* s7F = F + 6*SLOT; float* hF  = F + 7*SLOT;
  short* s0B = Bb;          short* s1B = Bb + SLOT;   short* s2B = Bb + 2*SLOT;
  short* s3B = Bb + 3*SLOT; short* s5B = Bb + 4*SLOT; short* hB  = Bb + 5*SLOT;

  unsigned target = 0;

  for (int t=0; t<TLEN; t++){
    // ---- P0: ch=[x_t|h]@W0 ; s0 = h + sig(cC)*(tanh(cH)-h). K=2048, 512 jobs.
    if (wv < 2){
      int j = wg*2 + wv; int col0 = (j & 63) << 4, r0 = (j >> 6) << 4;
      f32x4 aC = {0.f,0.f,0.f,0.f}, aH = {0.f,0.f,0.f,0.f};
      const short* wc = W0T + ((size_t)(col0+m) << 11) + (q << 3);
      const short* wh = wc + (1u << 21);
      const float* xp = x + (((size_t)(r0+m)*TLEN + t) << 10) + (q << 3);
      #pragma unroll 2
      for (int k0=0; k0<1024; k0+=32){
        float4 u0 = *(const float4*)(xp + k0);
        float4 u1 = *(const float4*)(xp + k0 + 4);
        bf16x8 a;
        a[0]=f2bf(u0.x); a[1]=f2bf(u0.y); a[2]=f2bf(u0.z); a[3]=f2bf(u0.w);
        a[4]=f2bf(u1.x); a[5]=f2bf(u1.y); a[6]=f2bf(u1.z); a[7]=f2bf(u1.w);
        bf16x8 bc = *(const bf16x8*)(wc + k0);
        bf16x8 bh = *(const bf16x8*)(wh + k0);
        aC = __builtin_amdgcn_mfma_f32_16x16x32_bf16(a, bc, aC, 0, 0, 0);
        aH = __builtin_amdgcn_mfma_f32_16x16x32_bf16(a, bh, aH, 0, 0, 0);
      }
      const short* hp = hB + ((size_t)(r0+m) << 10) + (q << 3);
      #pragma unroll 2
      for (int k0=0; k0<1024; k0+=32){
        bf16x8 a = *(const bf16x8*)(hp + k0);
        bf16x8 bc = *(const bf16x8*)(wc + 1024 + k0);
        bf16x8 bh = *(const bf16x8*)(wh + 1024 + k0);
        aC = __builtin_amdgcn_mfma_f32_16x16x32_bf16(a, bc, aC, 0, 0, 0);
        aH = __builtin_amdgcn_mfma_f32_16x16x32_bf16(a, bh, aH, 0, 0, 0);
      }
      #pragma unroll
      for (int i=0;i<4;i++){
        size_t o = (size_t)(r0 + (q<<2) + i)*NH + col0 + m;
        float hv = hF[o];
        float v = hv + sigf(aC[i])*(tanhf(aH[i]) - hv);
        s0F[o] = v; s0B[o] = f2bf(v);
      }
    }
    target += NWG; gsync(cnt, target);

    // ---- P1: g0 (sigmoid): s1 = s0 + sig(C)*(sig(H)-s0). 512 jobs.
    if (wv < 2){
      int j = wg*2 + wv; int col0 = (j & 63) << 4, r0 = (j >> 6) << 4;
      f32x4 aC[1] = {{0.f,0.f,0.f,0.f}}, aH[1] = {{0.f,0.f,0.f,0.f}};
      const int gs[1] = {0};
      mm_g<1>(s0B, WsT, gs, col0, r0, m, q, aC, aH);
      #pragma unroll
      for (int i=0;i<4;i++){
        size_t o = (size_t)(r0 + (q<<2) + i)*NH + col0 + m;
        float sp = s0F[o];
        float v = sp + sigf(aC[0][i])*(sigf(aH[0][i]) - sp);
        s1F[o] = v; s1B[o] = f2bf(v);
      }
    }
    target += NWG; gsync(cnt, target);

    // ---- P2: g1(relu),g2(relu),g3(identity), all A=sprev=s1. 512 fused jobs.
    if (wv < 2){
      int j = wg*2 + wv; int col0 = (j & 63) << 4, r0 = (j >> 6) << 4;
      f32x4 aC[3] = {{0.f,0.f,0.f,0.f},{0.f,0.f,0.f,0.f},{0.f,0.f,0.f,0.f}};
      f32x4 aH[3] = {{0.f,0.f,0.f,0.f},{0.f,0.f,0.f,0.f},{0.f,0.f,0.f,0.f}};
      const int gs[3] = {1,2,3};
      mm_g<3>(s1B, WsT, gs, col0, r0, m, q, aC, aH);
      #pragma unroll
      for (int i=0;i<4;i++){
        size_t o = (size_t)(r0 + (q<<2) + i)*NH + col0 + m;
        float sp = s1F[o];
        float v1 = sp + sigf(aC[0][i])*(fmaxf(aH[0][i],0.f) - sp);
        float v2 = sp + sigf(aC[1][i])*(fmaxf(aH[1][i],0.f) - sp);
        float v3 = sp + sigf(aC[2][i])*(aH[2][i] - sp);
        s2F[o] = v1; s2B[o] = f2bf(v1);
        s3F[o] = v2; s3B[o] = f2bf(v2);
        s4F[o] = v3;
      }
    }
    target += NWG; gsync(cnt, target);

    // ---- P3: g4(tanh, A=s2) and g6(tanh, A=s3). 1024 jobs, all waves.
    {
      int j = wg*4 + wv; int gene = (j < 512) ? 4 : 6; int jj = j & 511;
      int col0 = (jj & 63) << 4, r0 = (jj >> 6) << 4;
      const short* Ab = (gene==4) ? s2B : s3B;
      const float* Sp = (gene==4) ? s2F : s3F;
      f32x4 aC[1] = {{0.f,0.f,0.f,0.f}}, aH[1] = {{0.f,0.f,0.f,0.f}};
      const int gs[1] = {gene};
      mm_g<1>(Ab, WsT, gs, col0, r0, m, q, aC, aH);
      #pragma unroll
      for (int i=0;i<4;i++){
        size_t o = (size_t)(r0 + (q<<2) + i)*NH + col0 + m;
        float sp = Sp[o];
        float v = sp + sigf(aC[0][i])*(tanhf(aH[0][i]) - sp);
        if (gene==4){ s5F[o] = v; s5B[o] = f2bf(v); }
        else        { s7F[o] = v; }
      }
    }
    target += NWG; gsync(cnt, target);

    // ---- P4: g5(sigmoid) + g7(relu), A=sprev=s5; s6,s8 inline; mean -> h, out.
    if (wv < 2){
      int j = wg*2 + wv; int col0 = (j & 63) << 4, r0 = (j >> 6) << 4;
      f32x4 aC[2] = {{0.f,0.f,0.f,0.f},{0.f,0.f,0.f,0.f}};
      f32x4 aH[2] = {{0.f,0.f,0.f,0.f},{0.f,0.f,0.f,0.f}};
      const int gs[2] = {5,7};
      mm_g<2>(s5B, WsT, gs, col0, r0, m, q, aC, aH);
      #pragma unroll
      for (int i=0;i<4;i++){
        int b = r0 + (q<<2) + i, jc = col0 + m;
        size_t o = (size_t)b*NH + jc;
        float s5v = s5F[o];
        float s6v = s5v + sigf(aC[0][i])*(sigf(aH[0][i]) - s5v);
        float s8v = s5v + sigf(aC[1][i])*(fmaxf(aH[1][i],0.f) - s5v);
        float mn = (s1F[o]+s2F[o]+s3F[o]+s4F[o]+s5v+s6v+s7F[o]+s8v) * 0.125f;
        hF[o] = mn; hB[o] = f2bf(mn);
        out[((size_t)b*TLEN + t)*NH + jc] = mn;
        if (t == TLEN-1) out[(size_t)BSZ*TLEN*NH + o] = mn;
      }
    }
    target += NWG; gsync(cnt, target);
  }
}

extern "C" void kernel_launch(void* const* d_in, const int* in_sizes, int n_in,
                              void* d_out, int out_size, void* d_ws, size_t ws_size,
                              hipStream_t stream) {
  const float* x  = (const float*)d_in[0];   // (128, 256, 1024)
  const float* h0 = (const float*)d_in[1];   // (1, 128, 1024)
  const float* W0 = (const float*)d_in[2];   // (2048, 2048)
  const float* Ws = (const float*)d_in[3];   // (8, 1024, 2048)
  float* out = (float*)d_out;

  // ws: [0) W0T 8MB | [8M) WsT 32MB | [40M) F fp32 8 slots 4MB | [44M) Bb bf16 6 slots 1.5MB | [45.5M) counter
  char* wsb = (char*)d_ws;
  short* W0T = (short*)wsb;
  short* WsT = (short*)(wsb + (size_t)8*1024*1024);
  float* F   = (float*)(wsb + (size_t)40*1024*1024);
  short* Bb  = (short*)(wsb + (size_t)44*1024*1024);
  unsigned* cnt = (unsigned*)(wsb + (size_t)45*1024*1024 + 512*1024);

  transpose_bf16<<<dim3(64,64,1),256,0,stream>>>(W0, W0T, 2048);
  transpose_bf16<<<dim3(64,32,8),256,0,stream>>>(Ws, WsT, 1024);
  init_h<<<dim3(512),256,0,stream>>>(h0, F + (size_t)7*SLOT, Bb + (size_t)5*SLOT);
  hipMemsetAsync(cnt, 0, 64, stream);

  rnn_persistent<<<dim3(NWG),256,0,stream>>>(x, W0T, WsT, F, Bb, out, cnt);
}